// Round 10
// baseline (167.273 us; speedup 1.0000x reference)
//
#include <hip/hip_runtime.h>
#include <stdint.h>

typedef _Float16 f16;
typedef f16 f16x8 __attribute__((ext_vector_type(8)));
typedef float f32x4 __attribute__((ext_vector_type(4)));

#define NUM_NODES 20000
#define NUM_EDGES 65536
#define WIDTH 64
#define EDGE_FEAT 6
#define HIDDEN 128
#define BM 128            // edges per workgroup (grid 512, 2 async blocks/CU)
#define NCHUNK 129        // 128 h-chunks + 1 bias chunk
#define XPAD 72           // x-tile row stride in halfs
#define HPAD 130          // hbuf row stride in halfs

#define XH_HALFS (NUM_NODES * WIDTH)   // 1,280,000 halfs for x in f16
#define XCONV_BLKS 625                 // 625 * 2048 halfs = 1,280,000 exactly
#define W2G_HALFS (NCHUNK * 4096)      // 528,384 halfs
#define OUT_FLOATS (NUM_NODES * WIDTH) // 1,280,000
#define ZBLKS 313                      // 313 * 4096 >= OUT_FLOATS

// direct global->LDS DMA, 16B per lane. lds dest wave-uniform; HW adds lane*16.
__device__ __forceinline__ void gload_lds16(const f16* g, f16* l) {
  __builtin_amdgcn_global_load_lds(
      (const __attribute__((address_space(1))) unsigned int*)g,
      (__attribute__((address_space(3))) unsigned int*)l, 16, 0, 0);
}

// ---------------------------------------------------------------------------
// Prep: (a) W2g: 129 chunks of [64n x 64k] f16, transposed + XOR-granule
//       swizzled (chunk 128 = bias b2); (b) x fp32->f16; (c) zero `out`.
// ---------------------------------------------------------------------------
__global__ __launch_bounds__(256) void prep_kernel(
    const float* __restrict__ x, const float* __restrict__ W2,
    const float* __restrict__ b2, f16* __restrict__ ws_h,
    float* __restrict__ out)
{
  f16* x_h = ws_h;
  f16* W2g = ws_h + XH_HALFS;
  const int blk = blockIdx.x, tid = threadIdx.x;

  if (blk < NCHUNK) {
    __shared__ float row[4096];
    const int ki = blk;
    const float* srcrow;
    if (ki < HIDDEN) {
      const float4* src = (const float4*)(W2 + (size_t)ki * 4096);
      #pragma unroll
      for (int i = 0; i < 4; ++i) {
        float4 v = src[tid + 256 * i];
        *(float4*)&row[(tid + 256 * i) * 4] = v;
      }
      __syncthreads();
      srcrow = row;
    } else {
      srcrow = b2;  // bias chunk
    }
    const int obase = tid * 16;
    f16x8 outv0, outv1;
    #pragma unroll
    for (int u = 0; u < 8; ++u) {
      int o = obase + u;
      int n = o >> 6, pg = (o >> 3) & 7, j = o & 7;
      int k = (pg ^ (n & 7)) * 8 + j;
      outv0[u] = (f16)srcrow[k * 64 + n];
    }
    #pragma unroll
    for (int u = 0; u < 8; ++u) {
      int o = obase + 8 + u;
      int n = o >> 6, pg = (o >> 3) & 7, j = o & 7;
      int k = (pg ^ (n & 7)) * 8 + j;
      outv1[u] = (f16)srcrow[k * 64 + n];
    }
    *(f16x8*)&W2g[(size_t)ki * 4096 + obase] = outv0;
    *(f16x8*)&W2g[(size_t)ki * 4096 + obase + 8] = outv1;
  } else if (blk < NCHUNK + XCONV_BLKS) {
    int idx = (blk - NCHUNK) * 2048 + tid * 8;
    if (idx + 8 <= XH_HALFS) {
      float4 a = *(const float4*)(x + idx);
      float4 b = *(const float4*)(x + idx + 4);
      f16x8 hv;
      hv[0] = (f16)a.x; hv[1] = (f16)a.y; hv[2] = (f16)a.z; hv[3] = (f16)a.w;
      hv[4] = (f16)b.x; hv[5] = (f16)b.y; hv[6] = (f16)b.z; hv[7] = (f16)b.w;
      *(f16x8*)&x_h[idx] = hv;
    }
  } else {
    int base = (blk - NCHUNK - XCONV_BLKS) * 4096 + tid * 16;
    float4 z = {0.f, 0.f, 0.f, 0.f};
    #pragma unroll
    for (int i = 0; i < 4; ++i) {
      int idx = base + i * 4;
      if (idx + 4 <= OUT_FLOATS) *(float4*)(out + idx) = z;
    }
  }
}

// ---------------------------------------------------------------------------
// Main kernel: grid 512, 256 thr (4 waves), 2 ASYNC blocks/CU, full K.
// Wave (mhalf,nhalf) = 64 edges x 32 cols; 16 MFMA per chunk.
// r10 = r9 + ONE-CHUNK REGISTER PREFETCH: at iter k, compute chunk k from
// registers (bf/hv read LAST iter) while issuing ds_reads for k+1 and DMA
// for k+2. ds latency hides under MFMA; top-of-iter lgkmcnt(0)/vmcnt(0)
// drain ~500-cyc-old ops (free). 3-slot ring, 6x unrolled, static A/B regs.
// ---------------------------------------------------------------------------
__global__ __launch_bounds__(256, 2) void nnconv_kernel(
    const float* __restrict__ ea, const float* __restrict__ W1,
    const float* __restrict__ b1, const int* __restrict__ senders,
    const int* __restrict__ receivers, const f16* __restrict__ ws_h,
    float* __restrict__ out)
{
  const f16* x_h = ws_h;
  const f16* W2g = ws_h + XH_HALFS;
  __shared__ __align__(16) f16 xt[BM][XPAD];       // 18,432 B
  __shared__ __align__(16) f16 hbuf[HIDDEN * HPAD];// 33,280 B
  __shared__ __align__(16) f16 ring[3 * 4096];     // 24,576 B (76,288 total)

  const int tid = threadIdx.x;
  const int lane = tid & 63, wid = tid >> 6;
  const int quad = lane >> 4, l15 = lane & 15;
  const int mhalf = wid >> 1, nhalf = wid & 1;
  const int e0 = blockIdx.x * BM;
  const int mbase = mhalf * 64;

  // per-wave DMA slice: 1024 halfs of each 4096-half chunk
  const f16* wsrc = W2g + wid * 1024 + (lane << 3);
  const int stg_off = wid * 1024;          // wave-uniform LDS offset (halfs)

  // ---- prologue stage: chunks 0,1 -> slots 0,1  (4 DMA)
  gload_lds16(wsrc, &ring[stg_off]);
  gload_lds16(wsrc + 512, &ring[stg_off + 512]);
  gload_lds16(wsrc + 4096, &ring[4096 + stg_off]);
  gload_lds16(wsrc + 4096 + 512, &ring[4096 + stg_off + 512]);

  // ---- ea rows for this block -> LDS (aliases ring slot 2; freed pre-loop)
  float* eaf = (float*)&ring[2 * 4096];    // 768 f32 = 3072 B
  if (tid < 192)
    ((float4*)eaf)[tid] = ((const float4*)(ea + (size_t)e0 * EDGE_FEAT))[tid];

  // ---- gather sender x rows (f16) into LDS: 2 threads per row, 64B each
  {
    int r = tid >> 1, half = tid & 1;
    int s = senders[e0 + r];
    const uint4* src = (const uint4*)(x_h + (size_t)s * WIDTH + half * 32);
    uint4* dst = (uint4*)&xt[r][half * 32];
    #pragma unroll
    for (int i = 0; i < 4; ++i) dst[i] = src[i];
  }

  __syncthreads();  // eaf + xt ready (also drains prologue stages)

  // ---- h precompute: thread (k = tid>>1, half) does 64 edges of row k
  {
    const int k = tid >> 1, half = tid & 1;
    float b1c = b1[k];
    float w1c[6];
    #pragma unroll
    for (int f = 0; f < 6; ++f) w1c[f] = W1[f * HIDDEN + k];
    f16* hrow = &hbuf[k * HPAD + half * 64];
    const float* er = eaf + half * 64 * EDGE_FEAT;
    #pragma unroll 2
    for (int g8 = 0; g8 < 8; ++g8) {
      f16x8 hv;
      #pragma unroll
      for (int j = 0; j < 8; ++j) {
        const float* p = er + (g8 * 8 + j) * EDGE_FEAT;
        float s = b1c;
        #pragma unroll
        for (int f = 0; f < 6; ++f) s = fmaf(p[f], w1c[f], s);
        hv[j] = (f16)fmaxf(s, 0.f);
      }
      *(f16x8*)&hrow[g8 * 8] = hv;
    }
  }

  // ---- x fragments (A: m=l15, k-octet=quad), held in regs all loop
  f16x8 xf[4][2];
  #pragma unroll
  for (int t = 0; t < 4; ++t)
    #pragma unroll
    for (int kc = 0; kc < 2; ++kc)
      xf[t][kc] = *(const f16x8*)&xt[mbase + t * 16 + l15][kc * 32 + quad * 8];

  // ---- per-lane B-fragment offsets within a chunk (swizzled), in halfs
  int boff[2][2];
  #pragma unroll
  for (int kc = 0; kc < 2; ++kc)
    #pragma unroll
    for (int nt = 0; nt < 2; ++nt) {
      int n = nhalf * 32 + nt * 16 + l15;
      int g = kc * 4 + quad;
      boff[kc][nt] = n * 64 + (g ^ (n & 7)) * 8;
    }

  const f16* hb = &hbuf[mbase + l15];      // hb[k*HPAD + t*16]

  f32x4 acc[4][2];
  #pragma unroll
  for (int t = 0; t < 4; ++t)
    #pragma unroll
    for (int nt = 0; nt < 2; ++nt)
      acc[t][nt] = (f32x4){0.f, 0.f, 0.f, 0.f};

  __syncthreads();  // hbuf ready; eaf dead -> slot 2 reusable

  // ---- preload chunk 0 -> register set A (slot 0 staged, drained at sync#1)
  f16x8 bfA[2][2], bfB[2][2];
  f16 hvA[4], hvB[4];
  #pragma unroll
  for (int kc = 0; kc < 2; ++kc)
    #pragma unroll
    for (int nt = 0; nt < 2; ++nt)
      bfA[kc][nt] = *(const f16x8*)&ring[boff[kc][nt]];
  #pragma unroll
  for (int t = 0; t < 4; ++t) hvA[t] = hb[t * 16];

  // STEP(K): compute chunk K from (CB,CH); ds_read chunk K+1 from RSLOT into
  // (NB,NH); DMA chunk K+2 into SDST. vmcnt(0): DMA(K+1) is 1 iter old.
#define STEP(K, CB, CH, NB, NH, RSLOT, STG, SDST)                             \
  {                                                                           \
    asm volatile("s_waitcnt vmcnt(0) lgkmcnt(0)\n\ts_barrier" ::: "memory");  \
    __builtin_amdgcn_sched_barrier(0);                                        \
    if (STG) {                                                                \
      const f16* s_ = wsrc + (size_t)((K) + 2) * 4096;                        \
      f16* d_ = &ring[(SDST) * 4096 + stg_off];                               \
      gload_lds16(s_, d_);                                                    \
      gload_lds16(s_ + 512, d_ + 512);                                        \
    }                                                                         \
    __builtin_amdgcn_sched_barrier(0);                                        \
    {                                                                         \
      const f16* rb_ = &ring[(RSLOT) * 4096];                                 \
      _Pragma("unroll") for (int kc = 0; kc < 2; ++kc)                        \
        _Pragma("unroll") for (int nt = 0; nt < 2; ++nt)                      \
          NB[kc][nt] = *(const f16x8*)&rb_[boff[kc][nt]];                     \
      const int hk_ = ((K) + 1 < 128) ? (K) + 1 : 127;                        \
      _Pragma("unroll") for (int t = 0; t < 4; ++t)                           \
        NH[t] = hb[hk_ * HPAD + t * 16];                                      \
    }                                                                         \
    __builtin_amdgcn_sched_barrier(0);                                        \
    f16x8 sa0_[4], sa1_[4];                                                   \
    _Pragma("unroll") for (int t = 0; t < 4; ++t) {                           \
      sa0_[t] = xf[t][0] * CH[t];                                             \
      sa1_[t] = xf[t][1] * CH[t];                                             \
    }                                                                         \
    __builtin_amdgcn_s_setprio(1);                                            \
    _Pragma("unroll") for (int t = 0; t < 4; ++t)                             \
      _Pragma("unroll") for (int nt = 0; nt < 2; ++nt)                        \
        acc[t][nt] = __builtin_amdgcn_mfma_f32_16x16x32_f16(                  \
            sa0_[t], CB[0][nt], acc[t][nt], 0, 0, 0);                         \
    _Pragma("unroll") for (int t = 0; t < 4; ++t)                             \
      _Pragma("unroll") for (int nt = 0; nt < 2; ++nt)                        \
        acc[t][nt] = __builtin_amdgcn_mfma_f32_16x16x32_f16(                  \
            sa1_[t], CB[1][nt], acc[t][nt], 0, 0, 0);                         \
    __builtin_amdgcn_s_setprio(0);                                            \
  }

  // ---- main loop: chunks 0..125, 6x unrolled (all slots static)
  #pragma unroll 1
  for (int kb = 0; kb < 126; kb += 6) {
    STEP(kb + 0, bfA, hvA, bfB, hvB, 1, 1, 2);
    STEP(kb + 1, bfB, hvB, bfA, hvA, 2, 1, 0);
    STEP(kb + 2, bfA, hvA, bfB, hvB, 0, 1, 1);
    STEP(kb + 3, bfB, hvB, bfA, hvA, 1, 1, 2);
    STEP(kb + 4, bfA, hvA, bfB, hvB, 2, 1, 0);
    STEP(kb + 5, bfB, hvB, bfA, hvA, 0, 1, 1);
  }
  // chunk 126 (A; reads 127->B; DMA 128->slot2), chunk 127 (B; reads 128->A)
  STEP(126, bfA, hvA, bfB, hvB, 1, 1, 2);
  STEP(127, bfB, hvB, bfA, hvA, 2, 0, 0);
#undef STEP

  // ---- tail: chunk 128 (bias row, h == 1) from register set A
  __builtin_amdgcn_s_setprio(1);
  #pragma unroll
  for (int t = 0; t < 4; ++t)
    #pragma unroll
    for (int nt = 0; nt < 2; ++nt) {
      acc[t][nt] = __builtin_amdgcn_mfma_f32_16x16x32_f16(
          xf[t][0], bfA[0][nt], acc[t][nt], 0, 0, 0);
      acc[t][nt] = __builtin_amdgcn_mfma_f32_16x16x32_f16(
          xf[t][1], bfA[1][nt], acc[t][nt], 0, 0, 0);
    }
  __builtin_amdgcn_s_setprio(0);

  // ---- epilogue: C row = quad*4 + reg, col = l15; scatter-add (full sums)
  #pragma unroll
  for (int t = 0; t < 4; ++t) {
    int ebase = e0 + mbase + t * 16 + quad * 4;
    int rc[4];
    #pragma unroll
    for (int r = 0; r < 4; ++r) rc[r] = receivers[ebase + r];
    #pragma unroll
    for (int nt = 0; nt < 2; ++nt) {
      int v = (nhalf * 2 + nt) * 16 + l15;
      #pragma unroll
      for (int r = 0; r < 4; ++r)
        atomicAdd(out + (size_t)rc[r] * WIDTH + v, acc[t][nt][r]);
    }
  }
}

extern "C" void kernel_launch(void* const* d_in, const int* in_sizes, int n_in,
                              void* d_out, int out_size, void* d_ws, size_t ws_size,
                              hipStream_t stream) {
  const float* x  = (const float*)d_in[0];
  const float* ea = (const float*)d_in[1];
  const float* W1 = (const float*)d_in[2];
  const float* b1 = (const float*)d_in[3];
  const float* W2 = (const float*)d_in[4];
  const float* b2 = (const float*)d_in[5];
  const int* snd  = (const int*)d_in[6];
  const int* rcv  = (const int*)d_in[7];
  float* out = (float*)d_out;
  f16* wsh = (f16*)d_ws;

  const int prep_grid = NCHUNK + XCONV_BLKS + ZBLKS;
  prep_kernel<<<prep_grid, 256, 0, stream>>>(x, W2, b2, wsh, out);
  nnconv_kernel<<<NUM_EDGES / BM, 256, 0, stream>>>(ea, W1, b1, snd, rcv, wsh, out);
}

// Round 11
// 150.253 us; speedup vs baseline: 1.1133x; 1.1133x over previous
//
#include <hip/hip_runtime.h>
#include <stdint.h>

typedef _Float16 f16;
typedef f16 f16x8 __attribute__((ext_vector_type(8)));
typedef float f32x4 __attribute__((ext_vector_type(4)));

#define NUM_NODES 20000
#define NUM_EDGES 65536
#define WIDTH 64
#define EDGE_FEAT 6
#define HIDDEN 128
#define BM 128            // edges per workgroup (grid 512, 2 blocks/CU)
#define NCHUNK 129        // 128 h-chunks + 1 bias chunk

#define XH_HALFS (NUM_NODES * WIDTH)   // 1,280,000 halfs for x in f16
#define XCONV_BLKS 625                 // 625 * 2048 halfs = 1,280,000 exactly
#define W2G_HALFS (NCHUNK * 4096)      // 528,384 halfs
#define OUT_FLOATS (NUM_NODES * WIDTH) // 1,280,000
#define ZBLKS 313                      // 313 * 4096 >= OUT_FLOATS

// direct global->LDS DMA, 16B per lane. lds dest wave-uniform; HW adds lane*16.
__device__ __forceinline__ void gload_lds16(const f16* g, f16* l) {
  __builtin_amdgcn_global_load_lds(
      (const __attribute__((address_space(1))) unsigned int*)g,
      (__attribute__((address_space(3))) unsigned int*)l, 16, 0, 0);
}

// ---------------------------------------------------------------------------
// Prep: (a) W2g: 129 chunks of [64n x 64k] f16, transposed + XOR-granule
//       swizzled (chunk 128 = bias b2); (b) x fp32->f16; (c) zero `out`.
// ---------------------------------------------------------------------------
__global__ __launch_bounds__(256) void prep_kernel(
    const float* __restrict__ x, const float* __restrict__ W2,
    const float* __restrict__ b2, f16* __restrict__ ws_h,
    float* __restrict__ out)
{
  f16* x_h = ws_h;
  f16* W2g = ws_h + XH_HALFS;
  const int blk = blockIdx.x, tid = threadIdx.x;

  if (blk < NCHUNK) {
    __shared__ float row[4096];
    const int ki = blk;
    const float* srcrow;
    if (ki < HIDDEN) {
      const float4* src = (const float4*)(W2 + (size_t)ki * 4096);
      #pragma unroll
      for (int i = 0; i < 4; ++i) {
        float4 v = src[tid + 256 * i];
        *(float4*)&row[(tid + 256 * i) * 4] = v;
      }
      __syncthreads();
      srcrow = row;
    } else {
      srcrow = b2;  // bias chunk
    }
    const int obase = tid * 16;
    f16x8 outv0, outv1;
    #pragma unroll
    for (int u = 0; u < 8; ++u) {
      int o = obase + u;
      int n = o >> 6, pg = (o >> 3) & 7, j = o & 7;
      int k = (pg ^ (n & 7)) * 8 + j;
      outv0[u] = (f16)srcrow[k * 64 + n];
    }
    #pragma unroll
    for (int u = 0; u < 8; ++u) {
      int o = obase + 8 + u;
      int n = o >> 6, pg = (o >> 3) & 7, j = o & 7;
      int k = (pg ^ (n & 7)) * 8 + j;
      outv1[u] = (f16)srcrow[k * 64 + n];
    }
    *(f16x8*)&W2g[(size_t)ki * 4096 + obase] = outv0;
    *(f16x8*)&W2g[(size_t)ki * 4096 + obase + 8] = outv1;
  } else if (blk < NCHUNK + XCONV_BLKS) {
    int idx = (blk - NCHUNK) * 2048 + tid * 8;
    if (idx + 8 <= XH_HALFS) {
      float4 a = *(const float4*)(x + idx);
      float4 b = *(const float4*)(x + idx + 4);
      f16x8 hv;
      hv[0] = (f16)a.x; hv[1] = (f16)a.y; hv[2] = (f16)a.z; hv[3] = (f16)a.w;
      hv[4] = (f16)b.x; hv[5] = (f16)b.y; hv[6] = (f16)b.z; hv[7] = (f16)b.w;
      *(f16x8*)&x_h[idx] = hv;
    }
  } else {
    int base = (blk - NCHUNK - XCONV_BLKS) * 4096 + tid * 16;
    float4 z = {0.f, 0.f, 0.f, 0.f};
    #pragma unroll
    for (int i = 0; i < 4; ++i) {
      int idx = base + i * 4;
      if (idx + 4 <= OUT_FLOATS) *(float4*)(out + idx) = z;
    }
  }
}

// ---------------------------------------------------------------------------
// Main kernel: grid 512, 256 thr (4 waves), 2 blocks/CU, full K.
// Wave (mhalf,nhalf) = 64 edges x 32 cols; 16 MFMA per chunk.
// BARRIER-FREE K-LOOP: each wave DMAs its own 4 KB slice (nhalf's 32 cols,
// contiguous in W2g's n-major chunk) into a WAVE-PRIVATE 2-slot LDS ring,
// synced only by per-wave vmcnt:
//   iter k: s_waitcnt vmcnt(0)   // DMA(k), issued 1 iter ago, L2-hot: free
//           issue DMA(k+1) -> private slot (k+1)&1
//           ds_read bf/hv from slot k&1; pk_mul; 16 MFMA [setprio]
// No cross-wave coupling -> waves de-phase and the SIMD interleaves the two
// resident waves' MFMA bursts (the overlap every barrier variant lacked).
// Cost: B read 2x per block (mhalf pair) from the L2-resident 1 MB W2g.
// Tail: chunk 128 (bias, h==1) from slot 0.
// ---------------------------------------------------------------------------
__global__ __launch_bounds__(256, 2) void nnconv_kernel(
    const float* __restrict__ ea, const float* __restrict__ W1,
    const float* __restrict__ b1, const int* __restrict__ senders,
    const int* __restrict__ receivers, const f16* __restrict__ ws_h,
    float* __restrict__ out)
{
  const f16* x_h = ws_h;
  const f16* W2g = ws_h + XH_HALFS;
  __shared__ __align__(16) f16 xt[BM][64];          // 16,384 B (no pad)
  __shared__ __align__(16) f16 hbuf[HIDDEN * 128];  // 32,768 B
  __shared__ __align__(16) f16 ring[4 * 2 * 2048];  // 32,768 B (= 80 KB total)

  const int tid = threadIdx.x;
  const int lane = tid & 63, wid = tid >> 6;
  const int quad = lane >> 4, l15 = lane & 15;
  const int mhalf = wid >> 1, nhalf = wid & 1;
  const int e0 = blockIdx.x * BM;
  const int mbase = mhalf * 64;

  // ---- (1) stage ea rows into xt area (freed before x gather)
  float* eaf = (float*)&xt[0][0];    // 768 f32 = 3072 B
  if (tid < 192)
    ((float4*)eaf)[tid] = ((const float4*)(ea + (size_t)e0 * EDGE_FEAT))[tid];
  __syncthreads();

  // ---- (2) h precompute: thread (k = tid>>1, half) does 64 edges of row k
  {
    const int k = tid >> 1, half = tid & 1;
    float b1c = b1[k];
    float w1c[6];
    #pragma unroll
    for (int f = 0; f < 6; ++f) w1c[f] = W1[f * HIDDEN + k];
    f16* hrow = &hbuf[k * 128 + half * 64];
    const float* er = eaf + half * 64 * EDGE_FEAT;
    #pragma unroll 2
    for (int g8 = 0; g8 < 8; ++g8) {
      f16x8 hv;
      #pragma unroll
      for (int j = 0; j < 8; ++j) {
        const float* p = er + (g8 * 8 + j) * EDGE_FEAT;
        float s = b1c;
        #pragma unroll
        for (int f = 0; f < 6; ++f) s = fmaf(p[f], w1c[f], s);
        hv[j] = (f16)fmaxf(s, 0.f);
      }
      *(f16x8*)&hrow[g8 * 8] = hv;
    }
  }
  __syncthreads();  // eaf consumed; hbuf ready

  // ---- (3) x gather into xt (2 threads/row, 64 B each) + private DMA(0)
  {
    int r = tid >> 1, half = tid & 1;
    int s = senders[e0 + r];
    const uint4* src = (const uint4*)(x_h + (size_t)s * WIDTH + half * 32);
    uint4* dst = (uint4*)&xt[r][half * 32];
    #pragma unroll
    for (int i = 0; i < 4; ++i) dst[i] = src[i];
  }
  f16* myring = &ring[wid * 4096];                    // 2 slots x 2048 halfs
  const f16* wsl = W2g + nhalf * 2048 + (lane << 3);  // wave's slice base
  #pragma unroll
  for (int i = 0; i < 4; ++i)
    gload_lds16(wsl + i * 512, myring + i * 512);     // chunk 0 -> slot 0
  __syncthreads();  // xt visible to all waves (also drains DMA(0))

  // ---- x fragments (A: m=l15, k-octet=quad), held in regs all loop
  f16x8 xf[4][2];
  #pragma unroll
  for (int t = 0; t < 4; ++t)
    #pragma unroll
    for (int kc = 0; kc < 2; ++kc)
      xf[t][kc] = *(const f16x8*)&xt[mbase + t * 16 + l15][kc * 32 + quad * 8];

  // ---- per-lane B-fragment offsets within the PRIVATE 2048-half slice
  // slice-local col n' = nt*16 + l15 (n'&7 == l15&7)
  int boff[2][2];
  #pragma unroll
  for (int kc = 0; kc < 2; ++kc)
    #pragma unroll
    for (int nt = 0; nt < 2; ++nt) {
      int np = nt * 16 + l15;
      int g = kc * 4 + quad;
      boff[kc][nt] = np * 64 + (g ^ (np & 7)) * 8;
    }

  const f16* hb = &hbuf[mbase + l15];  // hv[t] = hb[k*128 + t*16]

  f32x4 acc[4][2];
  #pragma unroll
  for (int t = 0; t < 4; ++t)
    #pragma unroll
    for (int nt = 0; nt < 2; ++nt)
      acc[t][nt] = (f32x4){0.f, 0.f, 0.f, 0.f};

  // ---- barrier-free main loop: 128 chunks
  #pragma unroll 2
  for (int k = 0; k < 128; ++k) {
    // drain DMA(k) (issued 1 iter ago; prologue for k=0) -- per-wave only
    asm volatile("s_waitcnt vmcnt(0)" ::: "memory");
    __builtin_amdgcn_sched_barrier(0);
    // issue DMA(k+1) into the other private slot (chunk 128 = bias, valid)
    {
      const f16* src = wsl + (size_t)(k + 1) * 4096;
      f16* dst = myring + ((k + 1) & 1) * 2048;
      #pragma unroll
      for (int i = 0; i < 4; ++i)
        gload_lds16(src + i * 512, dst + i * 512);
    }
    __builtin_amdgcn_sched_barrier(0);

    // read this chunk's fragments from the private slot (compiler lgkmcnt)
    const f16* gb = myring + (k & 1) * 2048;
    f16x8 bf[2][2];
    #pragma unroll
    for (int kc = 0; kc < 2; ++kc)
      #pragma unroll
      for (int nt = 0; nt < 2; ++nt)
        bf[kc][nt] = *(const f16x8*)&gb[boff[kc][nt]];
    f16 hv[4];
    #pragma unroll
    for (int t = 0; t < 4; ++t) hv[t] = hb[k * 128 + t * 16];

    f16x8 sa0[4], sa1[4];
    #pragma unroll
    for (int t = 0; t < 4; ++t) {
      sa0[t] = xf[t][0] * hv[t];
      sa1[t] = xf[t][1] * hv[t];
    }
    __builtin_amdgcn_s_setprio(1);
    #pragma unroll
    for (int t = 0; t < 4; ++t)
      #pragma unroll
      for (int nt = 0; nt < 2; ++nt)
        acc[t][nt] = __builtin_amdgcn_mfma_f32_16x16x32_f16(
            sa0[t], bf[0][nt], acc[t][nt], 0, 0, 0);
    #pragma unroll
    for (int t = 0; t < 4; ++t)
      #pragma unroll
      for (int nt = 0; nt < 2; ++nt)
        acc[t][nt] = __builtin_amdgcn_mfma_f32_16x16x32_f16(
            sa1[t], bf[1][nt], acc[t][nt], 0, 0, 0);
    __builtin_amdgcn_s_setprio(0);
  }

  // ---- tail: chunk 128 (bias row, h == 1) from private slot 0
  asm volatile("s_waitcnt vmcnt(0)" ::: "memory");
  __builtin_amdgcn_sched_barrier(0);
  {
    f16x8 bf[2][2];
    #pragma unroll
    for (int kc = 0; kc < 2; ++kc)
      #pragma unroll
      for (int nt = 0; nt < 2; ++nt)
        bf[kc][nt] = *(const f16x8*)&myring[boff[kc][nt]];
    __builtin_amdgcn_s_setprio(1);
    #pragma unroll
    for (int t = 0; t < 4; ++t)
      #pragma unroll
      for (int nt = 0; nt < 2; ++nt) {
        acc[t][nt] = __builtin_amdgcn_mfma_f32_16x16x32_f16(
            xf[t][0], bf[0][nt], acc[t][nt], 0, 0, 0);
        acc[t][nt] = __builtin_amdgcn_mfma_f32_16x16x32_f16(
            xf[t][1], bf[1][nt], acc[t][nt], 0, 0, 0);
      }
    __builtin_amdgcn_s_setprio(0);
  }

  // ---- epilogue: C row = quad*4 + reg, col = l15; scatter-add (full sums)
  #pragma unroll
  for (int t = 0; t < 4; ++t) {
    int ebase = e0 + mbase + t * 16 + quad * 4;
    int rc[4];
    #pragma unroll
    for (int r = 0; r < 4; ++r) rc[r] = receivers[ebase + r];
    #pragma unroll
    for (int nt = 0; nt < 2; ++nt) {
      int v = (nhalf * 2 + nt) * 16 + l15;
      #pragma unroll
      for (int r = 0; r < 4; ++r)
        atomicAdd(out + (size_t)rc[r] * WIDTH + v, acc[t][nt][r]);
    }
  }
}

extern "C" void kernel_launch(void* const* d_in, const int* in_sizes, int n_in,
                              void* d_out, int out_size, void* d_ws, size_t ws_size,
                              hipStream_t stream) {
  const float* x  = (const float*)d_in[0];
  const float* ea = (const float*)d_in[1];
  const float* W1 = (const float*)d_in[2];
  const float* b1 = (const float*)d_in[3];
  const float* W2 = (const float*)d_in[4];
  const float* b2 = (const float*)d_in[5];
  const int* snd  = (const int*)d_in[6];
  const int* rcv  = (const int*)d_in[7];
  float* out = (float*)d_out;
  f16* wsh = (f16*)d_ws;

  const int prep_grid = NCHUNK + XCONV_BLKS + ZBLKS;
  prep_kernel<<<prep_grid, 256, 0, stream>>>(x, W2, b2, wsh, out);
  nnconv_kernel<<<NUM_EDGES / BM, 256, 0, stream>>>(ea, W1, b1, snd, rcv, wsh, out);
}

// Round 12
// 147.920 us; speedup vs baseline: 1.1308x; 1.0158x over previous
//
#include <hip/hip_runtime.h>
#include <stdint.h>

typedef _Float16 f16;
typedef f16 f16x8 __attribute__((ext_vector_type(8)));
typedef float f32x4 __attribute__((ext_vector_type(4)));

#define NUM_NODES 20000
#define NUM_EDGES 65536
#define WIDTH 64
#define EDGE_FEAT 6
#define HIDDEN 128
#define BM 128            // edges per workgroup (grid 512, 2 blocks/CU)
#define PADCH 132         // 128 h-chunks + bias + 3 zero pads (ring prefetch)

#define XH_HALFS (NUM_NODES * WIDTH)   // 1,280,000 halfs for x in f16
#define XCONV_BLKS 625                 // 625 * 2048 halfs = 1,280,000 exactly
#define OUT_FLOATS (NUM_NODES * WIDTH) // 1,280,000
#define ZBLKS 313                      // 313 * 4096 >= OUT_FLOATS

// direct global->LDS DMA, 16B per lane. lds dest wave-uniform; HW adds lane*16.
__device__ __forceinline__ void gload_lds16(const f16* g, f16* l) {
  __builtin_amdgcn_global_load_lds(
      (const __attribute__((address_space(1))) unsigned int*)g,
      (__attribute__((address_space(3))) unsigned int*)l, 16, 0, 0);
}

// ---------------------------------------------------------------------------
// Prep: (a) W2g: 132 chunks of [64n x 64k] f16, transposed + XOR-granule
//       swizzled (chunk 128 = bias b2, 129..131 zeros); (b) x fp32->f16;
//       (c) zero `out`.
// ---------------------------------------------------------------------------
__global__ __launch_bounds__(256) void prep_kernel(
    const float* __restrict__ x, const float* __restrict__ W2,
    const float* __restrict__ b2, f16* __restrict__ ws_h,
    float* __restrict__ out)
{
  f16* x_h = ws_h;
  f16* W2g = ws_h + XH_HALFS;
  const int blk = blockIdx.x, tid = threadIdx.x;

  if (blk < PADCH) {
    const int ki = blk;
    if (ki > HIDDEN) {  // zero pad chunks 129..131
      f16x8 z;
      #pragma unroll
      for (int u = 0; u < 8; ++u) z[u] = (f16)0.f;
      *(f16x8*)&W2g[(size_t)ki * 4096 + tid * 16] = z;
      *(f16x8*)&W2g[(size_t)ki * 4096 + tid * 16 + 8] = z;
      return;
    }
    __shared__ float row[4096];
    const float* srcrow;
    if (ki < HIDDEN) {
      const float4* src = (const float4*)(W2 + (size_t)ki * 4096);
      #pragma unroll
      for (int i = 0; i < 4; ++i) {
        float4 v = src[tid + 256 * i];
        *(float4*)&row[(tid + 256 * i) * 4] = v;
      }
      __syncthreads();
      srcrow = row;
    } else {
      srcrow = b2;  // bias chunk
    }
    const int obase = tid * 16;
    f16x8 outv0, outv1;
    #pragma unroll
    for (int u = 0; u < 8; ++u) {
      int o = obase + u;
      int n = o >> 6, pg = (o >> 3) & 7, j = o & 7;
      int k = (pg ^ (n & 7)) * 8 + j;
      outv0[u] = (f16)srcrow[k * 64 + n];
    }
    #pragma unroll
    for (int u = 0; u < 8; ++u) {
      int o = obase + 8 + u;
      int n = o >> 6, pg = (o >> 3) & 7, j = o & 7;
      int k = (pg ^ (n & 7)) * 8 + j;
      outv1[u] = (f16)srcrow[k * 64 + n];
    }
    *(f16x8*)&W2g[(size_t)ki * 4096 + obase] = outv0;
    *(f16x8*)&W2g[(size_t)ki * 4096 + obase + 8] = outv1;
  } else if (blk < PADCH + XCONV_BLKS) {
    int idx = (blk - PADCH) * 2048 + tid * 8;
    if (idx + 8 <= XH_HALFS) {
      float4 a = *(const float4*)(x + idx);
      float4 b = *(const float4*)(x + idx + 4);
      f16x8 hv;
      hv[0] = (f16)a.x; hv[1] = (f16)a.y; hv[2] = (f16)a.z; hv[3] = (f16)a.w;
      hv[4] = (f16)b.x; hv[5] = (f16)b.y; hv[6] = (f16)b.z; hv[7] = (f16)b.w;
      *(f16x8*)&x_h[idx] = hv;
    }
  } else {
    int base = (blk - PADCH - XCONV_BLKS) * 4096 + tid * 16;
    float4 z = {0.f, 0.f, 0.f, 0.f};
    #pragma unroll
    for (int i = 0; i < 4; ++i) {
      int idx = base + i * 4;
      if (idx + 4 <= OUT_FLOATS) *(float4*)(out + idx) = z;
    }
  }
}

// ---------------------------------------------------------------------------
// Main kernel: grid 512, 512 thr (8 waves), 2 async blocks/CU (4 waves/SIMD).
// Wave (mq, nh) = 32 edges x 32 cols; 8 MFMA per phase (chunk).
// COUNTED-VMCNT PHASE LOOP (T3+T4 port; never drains to 0 in the loop):
//   phase k: s_waitcnt vmcnt(2)   // waits for STAGE(k), issued 3 phases ago
//            s_barrier             // all waves' stage(k) landed; slot (k+3)&3
//                                  //   free to overwrite (phase k-1 reads done)
//            STAGE(k+3) -> ring[(k+3)&3]   // ONE gload_lds per wave
//            ds_read bf (4x b128) + hv (2x u16); pk_mul; 8 MFMA [setprio]
// Prologue stages chunks 0,1,2; __syncthreads() zeroes the counter; loop
// invariant: at phase k the wait targets a 3-phase (~1800 cyc) old load.
// Tail: chunk 128 (bias, h==1) from slot 0.
// ---------------------------------------------------------------------------
__global__ __launch_bounds__(512, 4) void nnconv_kernel(
    const float* __restrict__ ea, const float* __restrict__ W1,
    const float* __restrict__ b1, const int* __restrict__ senders,
    const int* __restrict__ receivers, const f16* __restrict__ ws_h,
    float* __restrict__ out)
{
  const f16* x_h = ws_h;
  const f16* W2g = ws_h + XH_HALFS;
  __shared__ __align__(16) f16 xt[BM][64];          // 16,384 B
  __shared__ __align__(16) f16 hbuf[HIDDEN * 128];  // 32,768 B
  __shared__ __align__(16) f16 ring[4 * 4096];      // 32,768 B (80 KB total)

  const int tid = threadIdx.x;
  const int lane = tid & 63, wid = tid >> 6;
  const int quad = lane >> 4, l15 = lane & 15;
  const int mq = wid >> 1, nh = wid & 1;
  const int e0 = blockIdx.x * BM;
  const int mbase = mq * 32;

  // ---- (1) ea rows -> xt area (freed before x gather)
  float* eaf = (float*)&xt[0][0];    // 768 f32 = 3072 B
  if (tid < 192)
    ((float4*)eaf)[tid] = ((const float4*)(ea + (size_t)e0 * EDGE_FEAT))[tid];
  __syncthreads();

  // ---- (2) h precompute: thread (k = tid>>2, q4 = tid&3) does 32 edges
  {
    const int k = tid >> 2, q4 = tid & 3;
    float b1c = b1[k];
    float w1c[6];
    #pragma unroll
    for (int f = 0; f < 6; ++f) w1c[f] = W1[f * HIDDEN + k];
    f16* hrow = &hbuf[k * 128 + q4 * 32];
    const float* er = eaf + q4 * 32 * EDGE_FEAT;
    #pragma unroll
    for (int g8 = 0; g8 < 4; ++g8) {
      f16x8 hv;
      #pragma unroll
      for (int j = 0; j < 8; ++j) {
        const float* p = er + (g8 * 8 + j) * EDGE_FEAT;
        float s = b1c;
        #pragma unroll
        for (int f = 0; f < 6; ++f) s = fmaf(p[f], w1c[f], s);
        hv[j] = (f16)fmaxf(s, 0.f);
      }
      *(f16x8*)&hrow[g8 * 8] = hv;
    }
  }
  __syncthreads();  // eaf consumed; hbuf ready

  // ---- (3) x gather (4 threads/row, 32 B each) + prologue stages 0,1,2
  {
    int r = tid >> 2, q = tid & 3;
    int s = senders[e0 + r];
    const uint4* src = (const uint4*)(x_h + (size_t)s * WIDTH + q * 16);
    uint4* dst = (uint4*)&xt[r][q * 16];
    dst[0] = src[0];
    dst[1] = src[1];
  }
  const f16* wsl = W2g + wid * 512 + (lane << 3);  // wave's 512-half slice
  gload_lds16(wsl,            &ring[0 * 4096 + wid * 512]);
  gload_lds16(wsl + 1 * 4096, &ring[1 * 4096 + wid * 512]);
  gload_lds16(wsl + 2 * 4096, &ring[2 * 4096 + wid * 512]);
  __syncthreads();  // xt visible; vmcnt drained to 0 (loop invariant base)

  // ---- x fragments (A: m=l15, k-octet=quad), held in regs all loop
  f16x8 xf[2][2];
  #pragma unroll
  for (int t = 0; t < 2; ++t)
    #pragma unroll
    for (int kc = 0; kc < 2; ++kc)
      xf[t][kc] = *(const f16x8*)&xt[mbase + t * 16 + l15][kc * 32 + quad * 8];

  // ---- per-lane B-fragment offsets within a chunk (swizzled), in halfs
  int boff[2][2];
  #pragma unroll
  for (int kc = 0; kc < 2; ++kc)
    #pragma unroll
    for (int nt = 0; nt < 2; ++nt) {
      int n = nh * 32 + nt * 16 + l15;
      int g = kc * 4 + quad;
      boff[kc][nt] = n * 64 + (g ^ (n & 7)) * 8;
    }

  const f16* hb = &hbuf[mbase + l15];  // hv[t] = hb[k*128 + t*16]

  f32x4 acc[2][2];
  #pragma unroll
  for (int t = 0; t < 2; ++t)
    #pragma unroll
    for (int nt = 0; nt < 2; ++nt)
      acc[t][nt] = (f32x4){0.f, 0.f, 0.f, 0.f};

  // ---- counted-vmcnt phase loop: 128 chunks
  #pragma unroll 4
  for (int k = 0; k < 128; ++k) {
    // wait for STAGE(k) (3 phases old); leave stages k+1,k+2 in flight
    asm volatile("s_waitcnt vmcnt(2)" ::: "memory");
    __builtin_amdgcn_s_barrier();
    __builtin_amdgcn_sched_barrier(0);
    // ONE DMA: stage chunk k+3 into slot (k+3)&3 (slot reads finished @ k-1)
    gload_lds16(wsl + (size_t)(k + 3) * 4096,
                &ring[((k + 3) & 3) * 4096 + wid * 512]);
    __builtin_amdgcn_sched_barrier(0);

    // this phase's fragments (compiler inserts lgkmcnt before MFMA)
    const f16* gb = &ring[(k & 3) * 4096];
    f16x8 bf[2][2];
    #pragma unroll
    for (int kc = 0; kc < 2; ++kc)
      #pragma unroll
      for (int nt = 0; nt < 2; ++nt)
        bf[kc][nt] = *(const f16x8*)&gb[boff[kc][nt]];
    f16 hv[2];
    #pragma unroll
    for (int t = 0; t < 2; ++t) hv[t] = hb[k * 128 + t * 16];

    f16x8 sa0[2], sa1[2];
    #pragma unroll
    for (int t = 0; t < 2; ++t) {
      sa0[t] = xf[t][0] * hv[t];
      sa1[t] = xf[t][1] * hv[t];
    }
    __builtin_amdgcn_s_setprio(1);
    #pragma unroll
    for (int t = 0; t < 2; ++t)
      #pragma unroll
      for (int nt = 0; nt < 2; ++nt)
        acc[t][nt] = __builtin_amdgcn_mfma_f32_16x16x32_f16(
            sa0[t], bf[0][nt], acc[t][nt], 0, 0, 0);
    #pragma unroll
    for (int t = 0; t < 2; ++t)
      #pragma unroll
      for (int nt = 0; nt < 2; ++nt)
        acc[t][nt] = __builtin_amdgcn_mfma_f32_16x16x32_f16(
            sa1[t], bf[1][nt], acc[t][nt], 0, 0, 0);
    __builtin_amdgcn_s_setprio(0);
  }

  // ---- tail: chunk 128 (bias row, h == 1) from slot 0 (staged @ phase 125)
  asm volatile("s_waitcnt vmcnt(2)" ::: "memory");
  __builtin_amdgcn_s_barrier();
  __builtin_amdgcn_sched_barrier(0);
  {
    f16x8 bf[2][2];
    #pragma unroll
    for (int kc = 0; kc < 2; ++kc)
      #pragma unroll
      for (int nt = 0; nt < 2; ++nt)
        bf[kc][nt] = *(const f16x8*)&ring[boff[kc][nt]];
    __builtin_amdgcn_s_setprio(1);
    #pragma unroll
    for (int t = 0; t < 2; ++t)
      #pragma unroll
      for (int nt = 0; nt < 2; ++nt) {
        acc[t][nt] = __builtin_amdgcn_mfma_f32_16x16x32_f16(
            xf[t][0], bf[0][nt], acc[t][nt], 0, 0, 0);
        acc[t][nt] = __builtin_amdgcn_mfma_f32_16x16x32_f16(
            xf[t][1], bf[1][nt], acc[t][nt], 0, 0, 0);
      }
    __builtin_amdgcn_s_setprio(0);
  }

  // ---- epilogue: C row = quad*4 + reg, col = l15; scatter-add (full sums)
  #pragma unroll
  for (int t = 0; t < 2; ++t) {
    int ebase = e0 + mbase + t * 16 + quad * 4;
    int rc[4];
    #pragma unroll
    for (int r = 0; r < 4; ++r) rc[r] = receivers[ebase + r];
    #pragma unroll
    for (int nt = 0; nt < 2; ++nt) {
      int v = nh * 32 + nt * 16 + l15;
      #pragma unroll
      for (int r = 0; r < 4; ++r)
        atomicAdd(out + (size_t)rc[r] * WIDTH + v, acc[t][nt][r]);
    }
  }
}

extern "C" void kernel_launch(void* const* d_in, const int* in_sizes, int n_in,
                              void* d_out, int out_size, void* d_ws, size_t ws_size,
                              hipStream_t stream) {
  const float* x  = (const float*)d_in[0];
  const float* ea = (const float*)d_in[1];
  const float* W1 = (const float*)d_in[2];
  const float* b1 = (const float*)d_in[3];
  const float* W2 = (const float*)d_in[4];
  const float* b2 = (const float*)d_in[5];
  const int* snd  = (const int*)d_in[6];
  const int* rcv  = (const int*)d_in[7];
  float* out = (float*)d_out;
  f16* wsh = (f16*)d_ws;

  const int prep_grid = PADCH + XCONV_BLKS + ZBLKS;
  prep_kernel<<<prep_grid, 256, 0, stream>>>(x, W2, b2, wsh, out);
  nnconv_kernel<<<NUM_EDGES / BM, 512, 0, stream>>>(ea, W1, b1, snd, rcv, wsh, out);
}